// Round 6
// baseline (6086.869 us; speedup 1.0000x reference)
//
#include <hip/hip_runtime.h>
#include <hip/hip_bf16.h>

#define NL 4
#define NB 4
#define NS 512
#define NH 1024
#define NV 32000
#define RING 32
#define SLICES 16        // per layer; 64 rows each
#define TPB 1024         // 16 waves

typedef unsigned int u32;
typedef unsigned short u16;
typedef unsigned long long u64;
typedef __attribute__((ext_vector_type(8))) __bf16 vbf16x8;
typedef __attribute__((ext_vector_type(8))) u16   vu16x8;
typedef __attribute__((ext_vector_type(4))) u32   vu32x4;
typedef __attribute__((ext_vector_type(4))) float vf32x4;

__device__ __forceinline__ u16 f2bf(float f) {
    u32 x = __builtin_bit_cast(u32, f);
    x += 0x7FFFu + ((x >> 16) & 1u);
    return (u16)(x >> 16);
}
__device__ __forceinline__ float softplus_f(float x) {
    return fmaxf(x, 0.0f) + log1pf(expf(-fabsf(x)));
}
__device__ __forceinline__ int aloadi(const int* p) {
    return __hip_atomic_load(p, __ATOMIC_RELAXED, __HIP_MEMORY_SCOPE_AGENT);
}
__device__ __forceinline__ u32 aload32(const u32* p) {
    return __hip_atomic_load(p, __ATOMIC_RELAXED, __HIP_MEMORY_SCOPE_AGENT);
}
__device__ __forceinline__ void astorei(int* p, int v) {
    __hip_atomic_store(p, v, __ATOMIC_RELAXED, __HIP_MEMORY_SCOPE_AGENT);
}
__device__ __forceinline__ void astore32(u32* p, u32 v) {
    __hip_atomic_store(p, v, __ATOMIC_RELAXED, __HIP_MEMORY_SCOPE_AGENT);
}

#define APAD 8
#define ASTR (NH + APAD)

// 64 blocks x 1024 threads. layer = bid&3, slice = bid>>2 (16 slices x 64 rows).
// Wave w: matrix m = w&3 (0=Ws,1=Us,2=twh,3=twu), rowgroup rg = w>>2 (16 rows).
// Handoff: seq-in-band dwords (bf16<<16 | seq) — data IS the flag, single
// one-way hop, no vmcnt/flag/RMW. Poll = 8 dwords/thread. Zeroed ring = h(0).
__global__ __launch_bounds__(TPB, 1) void lnn_recur(
    const int* __restrict__ ids, const float* __restrict__ emb,
    const float* __restrict__ Ws, const float* __restrict__ Us,
    const float* __restrict__ bsv, const float* __restrict__ twh,
    const float* __restrict__ twu, const float* __restrict__ tbv,
    const float* __restrict__ lambda_p,
    int* ack, u32* ring, u32* out_dw, float* hT_out)
{
    __shared__ __align__(16) u16 act_hp[5][ASTR];   // rows 0-3 = batch, row 4 = zeros
    __shared__ __align__(16) u16 act_in[5][ASTR];
    __shared__ float cross[4][4][16][4];            // [rg][mat][j][b]
    __shared__ float bias_a[64], bias_t[64];

    const int bid   = blockIdx.x;
    const int layer = bid & 3;
    const int slice = bid >> 2;
    const int j0    = slice << 6;                   // 64 rows per slice
    const int tid   = threadIdx.x;
    const int wave  = tid >> 6;
    const int lane  = tid & 63;
    const int m     = wave & 3;                     // matrix
    const int rg    = wave >> 2;                    // rowgroup

    // ---- resident weight fragments: 16 rows of matrix m, rowgroup rg ----
    const float* msel = (m == 0) ? Ws : (m == 1) ? Us : (m == 2) ? twh : twu;
    const float* mat  = msel + (size_t)layer * NH * NH;
    const int jr = j0 + rg * 16 + (lane & 15);      // B col = output row j
    const int kb = (lane >> 4) * 8;
    vbf16x8 wfrag[32];
#pragma unroll
    for (int c = 0; c < 32; ++c) {
        const float* s = mat + (size_t)jr * NH + c * 32 + kb;
        vu16x8 t8;
#pragma unroll
        for (int e = 0; e < 8; ++e) t8[e] = f2bf(s[e]);
        wfrag[c] = __builtin_bit_cast(vbf16x8, t8);
    }

    for (int i = tid; i < ASTR; i += TPB) { act_hp[4][i] = 0; act_in[4][i] = 0; }
    if (tid < 64) {
        bias_a[tid] = bsv[layer * NH + j0 + tid];
        bias_t[tid] = tbv[layer * NH + j0 + tid];
    }
    const float lam = softplus_f(lambda_p[0]);
    float hreg = 0.0f;                              // finalize waves (m==0): j=lane&15, b=lane>>4
    const int lm1 = (layer > 0) ? layer - 1 : 0;

    // poll/stage ownership: batch b = tid>>8, dword idx = (tid&255) + 256*q
    const int pb   = tid >> 8;
    const int pidx = tid & 255;

    for (int t = 0; t < NS; ++t) {
        const int slotH = (t - 1) & (RING - 1);
        const int slotI = t & (RING - 1);
        u32 hv[4], iv[4];

        // layer 0: emb gather + pack BEFORE polling (overlaps upstream wait)
        if (layer == 0) {
            const int v = ids[pb * NS + t];
            const float* er = emb + (size_t)v * NH + pidx;
#pragma unroll
            for (int q = 0; q < 4; ++q) iv[q] = ((u32)f2bf(er[256 * q])) << 16;
        }

        // ---- A: fused poll+load, 8 self-verifying dwords/thread, single hop ----
        {
            const u32* hbase = ring + (((size_t)(layer * NB + pb)) * RING + slotH) * NH + pidx;
            const u32* ibase = ring + (((size_t)(lm1   * NB + pb)) * RING + slotI) * NH + pidx;
            u32 pend = (layer > 0) ? 0xFFu : 0x0Fu;   // bits 0-3: h, bits 4-7: in
            const u32 seqH = (u32)t, seqI = (u32)(t + 1);
            const bool needAck = (layer < 3) && (t >= RING) && (lane < SLICES);
            const int  ackTgt  = t - RING + 1;
            const int* ackp    = ack + (layer + 1) * SLICES + (lane & 15);
            bool ackok = !needAck;
            for (int it = 0; it < (1 << 20); ++it) {
#pragma unroll
                for (int q = 0; q < 4; ++q) if (pend & (1u << q))       hv[q] = aload32(hbase + 256 * q);
#pragma unroll
                for (int q = 0; q < 4; ++q) if (pend & (1u << (4 + q))) iv[q] = aload32(ibase + 256 * q);
#pragma unroll
                for (int q = 0; q < 4; ++q) if ((pend & (1u << q)) && ((hv[q] & 0xFFFFu) == seqH)) pend &= ~(1u << q);
#pragma unroll
                for (int q = 0; q < 4; ++q) if ((pend & (1u << (4 + q))) && ((iv[q] & 0xFFFFu) == seqI)) pend &= ~(1u << (4 + q));
                if (needAck && !ackok) ackok = (aloadi(ackp) >= ackTgt);
                const bool done = (pend == 0u) & ackok;
                if (__all((int)done)) break;
                __builtin_amdgcn_s_sleep(1);
            }
        }

        // ---- B: stage to LDS (u16 writes, 2 lanes/bank = free) ----
        {
            u16* dh = &act_hp[pb][0];
            u16* di = &act_in[pb][0];
#pragma unroll
            for (int q = 0; q < 4; ++q) {
                dh[pidx + 256 * q] = (u16)(hv[q] >> 16);
                di[pidx + 256 * q] = (u16)(iv[q] >> 16);
            }
        }
        __syncthreads();
        if (tid == 0 && layer > 0) astorei(ack + layer * SLICES + slice, t + 1);   // consumed in(t)

        // ---- C: MFMA out[j,b] = sum_k act[b,k] * M[j,k]; 4 accumulators ----
        {
            const u16 (*asrc)[ASTR] = ((m & 1) == 0) ? act_hp : act_in;
            int ar = lane & 15; if (ar > 4) ar = 4;
            vf32x4 a0 = {0.f,0.f,0.f,0.f}, a1 = a0, a2 = a0, a3 = a0;
#pragma unroll
            for (int c = 0; c < 32; c += 4) {
                a0 = __builtin_amdgcn_mfma_f32_16x16x32_bf16(*(const vbf16x8*)&asrc[ar][(c+0)*32+kb], wfrag[c+0], a0, 0, 0, 0);
                a1 = __builtin_amdgcn_mfma_f32_16x16x32_bf16(*(const vbf16x8*)&asrc[ar][(c+1)*32+kb], wfrag[c+1], a1, 0, 0, 0);
                a2 = __builtin_amdgcn_mfma_f32_16x16x32_bf16(*(const vbf16x8*)&asrc[ar][(c+2)*32+kb], wfrag[c+2], a2, 0, 0, 0);
                a3 = __builtin_amdgcn_mfma_f32_16x16x32_bf16(*(const vbf16x8*)&asrc[ar][(c+3)*32+kb], wfrag[c+3], a3, 0, 0, 0);
            }
            vf32x4 acc = (a0 + a1) + (a2 + a3);
            if (lane < 16) {
#pragma unroll
                for (int r = 0; r < 4; ++r) cross[rg][m][lane][r] = acc[r];
            }
        }
        __syncthreads();

        // ---- D: finalize + publish (waves with m==0): one one-way store, no vmcnt/flag ----
        if (m == 0) {
            const int j = lane & 15, bb = lane >> 4;
            const int jg = j0 + rg * 16 + j;
            const float sa = cross[rg][0][j][bb] + cross[rg][1][j][bb] + bias_a[rg * 16 + j];
            const float st = cross[rg][2][j][bb] + cross[rg][3][j][bb] + bias_t[rg * 16 + j];
            const float tau = softplus_f(st) + 0.01f;
            const float av  = tanhf(sa);
            float dx = lam * (av - hreg / tau);
            dx = fminf(10.0f, fmaxf(-10.0f, dx));
            hreg = fmaf(0.1f, dx, hreg);
            const u16 hb = f2bf(hreg);
            astore32(ring + (((size_t)(layer * NB + bb)) * RING + slotI) * NH + jg,
                     ((u32)hb << 16) | (u32)(t + 1));
            if (layer == 3) {
                const u32 up = (u32)__shfl_down((int)hb, 1);
                if ((j & 1) == 0)
                    out_dw[((size_t)bb * NS + t) * 512 + (jg >> 1)] = (u32)hb | (up << 16);
            }
            if (t == NS - 1) hT_out[((size_t)layer * NB + bb) * NH + jg] = hreg;
        }
    }
}

// ---------------- projection GEMM: C[2048][32000] = A[2048][1024](bf16) * W[32000][1024]^T + b ----
#define BM 128
#define BN 128
#define BK 32
#define KSTEPS (NH / BK)
#define LSTR (BK + 8)

__global__ __launch_bounds__(256, 1) void proj_gemm(
    const u16* __restrict__ A, const float* __restrict__ Bw,
    const float* __restrict__ bias, float* __restrict__ C)
{
    __shared__ __align__(16) u16 Asm[2][BM][LSTR];
    __shared__ __align__(16) u16 Bsm[2][BN][LSTR];

    const int tid  = threadIdx.x;
    const int wave = tid >> 6, lane = tid & 63;
    const int wr = wave >> 1, wc = wave & 1;

    const int nwg = gridDim.x;
    const int id  = blockIdx.x;
    const int q = nwg >> 3, r = nwg & 7;
    const int x = id & 7, o = id >> 3;
    const int wg = (x < r ? x * (q + 1) : r * (q + 1) + (x - r) * q) + o;
    const int m0 = (wg & 15) * BM;
    const int n0 = (wg >> 4) * BN;

    const int srow  = tid >> 1;
    const int shalf = tid & 1;
    const u16*   agp = A  + (size_t)(m0 + srow) * NH + shalf * 16;
    const float* bgp = Bw + (size_t)(n0 + srow) * NH + shalf * 16;

    vf32x4 zed = {0.f, 0.f, 0.f, 0.f};
    vf32x4 acc[4][4];
#pragma unroll
    for (int m = 0; m < 4; ++m)
#pragma unroll
        for (int n = 0; n < 4; ++n) acc[m][n] = zed;

    vu32x4 areg0, areg1; vf32x4 breg0, breg1, breg2, breg3;
    auto load_tile = [&](int kt) {
        const u16* ap = agp + kt * BK;
        areg0 = *(const vu32x4*)ap;
        areg1 = *(const vu32x4*)(ap + 8);
        const float* bp = bgp + kt * BK;
        breg0 = *(const vf32x4*)bp;       breg1 = *(const vf32x4*)(bp + 4);
        breg2 = *(const vf32x4*)(bp + 8); breg3 = *(const vf32x4*)(bp + 12);
    };
    auto write_tile = [&](int buf) {
        u16* ad = &Asm[buf][srow][shalf * 16];
        *(vu32x4*)ad = areg0; *(vu32x4*)(ad + 8) = areg1;
        float fb[16];
        *(vf32x4*)&fb[0] = breg0; *(vf32x4*)&fb[4]  = breg1;
        *(vf32x4*)&fb[8] = breg2; *(vf32x4*)&fb[12] = breg3;
        vu16x8 v0, v1;
#pragma unroll
        for (int e = 0; e < 8; ++e) { v0[e] = f2bf(fb[e]); v1[e] = f2bf(fb[8 + e]); }
        u16* bd = &Bsm[buf][srow][shalf * 16];
        *(vu16x8*)bd = v0; *(vu16x8*)(bd + 8) = v1;
    };

    load_tile(0); write_tile(0);
    __syncthreads();

    const int fr = lane & 15;
    const int fk = (lane >> 4) * 8;
    for (int kt = 0; kt < KSTEPS; ++kt) {
        const int cur = kt & 1;
        if (kt + 1 < KSTEPS) load_tile(kt + 1);
        vbf16x8 afr[4], bfr[4];
#pragma unroll
        for (int mm = 0; mm < 4; ++mm)
            afr[mm] = *(const vbf16x8*)&Asm[cur][wr * 64 + mm * 16 + fr][fk];
#pragma unroll
        for (int n = 0; n < 4; ++n)
            bfr[n] = *(const vbf16x8*)&Bsm[cur][wc * 64 + n * 16 + fr][fk];
#pragma unroll
        for (int mm = 0; mm < 4; ++mm)
#pragma unroll
            for (int n = 0; n < 4; ++n)
                acc[mm][n] = __builtin_amdgcn_mfma_f32_16x16x32_bf16(afr[mm], bfr[n], acc[mm][n], 0, 0, 0);
        if (kt + 1 < KSTEPS) write_tile(cur ^ 1);
        __syncthreads();
    }

    const int cc = lane & 15;
    const int cr = (lane >> 4) * 4;
#pragma unroll
    for (int mm = 0; mm < 4; ++mm) {
#pragma unroll
        for (int n = 0; n < 4; ++n) {
            const int gc = n0 + wc * 64 + n * 16 + cc;
            const float bval = bias[gc];
            float* cp = C + (size_t)(m0 + wr * 64 + mm * 16 + cr) * NV + gc;
#pragma unroll
            for (int r = 0; r < 4; ++r)
                cp[(size_t)r * NV] = acc[mm][n][r] + bval;
        }
    }
}

extern "C" void kernel_launch(void* const* d_in, const int* in_sizes, int n_in,
                              void* d_out, int out_size, void* d_ws, size_t ws_size,
                              hipStream_t stream) {
    const int*   ids = (const int*)  d_in[0];
    const float* emb = (const float*)d_in[1];
    const float* pw  = (const float*)d_in[2];
    const float* pb  = (const float*)d_in[3];
    const float* lam = (const float*)d_in[4];
    const float* Ws  = (const float*)d_in[5];
    const float* Us  = (const float*)d_in[6];
    const float* bsv = (const float*)d_in[7];
    const float* twh = (const float*)d_in[8];
    const float* twu = (const float*)d_in[9];
    const float* tbv = (const float*)d_in[10];

    char* ws = (char*)d_ws;
    u32* ring   = (u32*)ws;                             // 4*4*32*1024*4 = 2 MB (seq-in-band)
    int* ack    = (int*)(ws + (2 << 20));               // 4*16*4 = 256 B (pad to 4 KB)
    u32* out_dw = (u32*)(ws + (2 << 20) + 4096);        // 2048*512*4 = 4 MB

    float* logits = (float*)d_out;
    float* hT     = logits + (size_t)NB * NS * NV;

    hipMemsetAsync(ws, 0, (2 << 20) + 4096, stream);    // ring seqs + acks, every call
    lnn_recur<<<dim3(NL * SLICES), dim3(TPB), 0, stream>>>(ids, emb, Ws, Us, bsv, twh, twu, tbv, lam,
                                                           ack, ring, out_dw, hT);
    proj_gemm<<<dim3((NV / BN) * ((NB * NS) / BM)), dim3(256), 0, stream>>>(
        (const u16*)out_dw, pw, pb, logits);
}